// Round 4
// baseline (457.848 us; speedup 1.0000x reference)
//
#include <hip/hip_runtime.h>
#include <hip/hip_bf16.h>

// Problem constants
#define H_    16
#define NOPE_ 128
#define ROPE_ 64
#define VDIM_ 128
#define LORA_ 512
#define DM_   2048
#define T_    256
#define S_    32768
#define K_    2048

static constexpr float SCALE_ = 0.072168783648703220563643597562744f; // 1/sqrt(192)
static constexpr float LOG2E_ = 1.4426950408889634f;

typedef __attribute__((ext_vector_type(8))) short short8;   // 8 bf16 in 4 VGPRs
typedef __attribute__((ext_vector_type(4))) short short4v;  // 4 bf16 in 2 VGPRs
typedef __attribute__((ext_vector_type(4))) float f32x4;    // MFMA accumulator

__device__ __forceinline__ ushort f2bf(float f) {
    unsigned u = __float_as_uint(f);
    unsigned r = (u + 0x7FFFu + ((u >> 16) & 1u)) >> 16;    // RNE
    return (ushort)r;
}
__device__ __forceinline__ float bf2f(ushort u) {
    return __uint_as_float((unsigned)u << 16);
}

// ---------------------------------------------------------------------------
// bf16 MFMA GEMM: C[M,N] = A[M,K] @ B[K,N] (B_NT: B is [N][K] n-major).
// BM=BN=64, BK=64, 256 thr (4 waves, each a 32x32 quadrant, 2x2 MFMA tiles).
// A fp32 or bf16 (A_BF16); B fp32; C fp32 or bf16 (C_BF16).
// LDS: As [m][k] bf16 pitch 72 (b128 frag reads, 2-way conflict = free);
//      Bs NT: [n][k] pitch 72 (b128 reads); NN: [k][n] pitch 68 (u16 reads).
// Layouts (HW-verified in attention): A[m=l&15][k=(l>>4)*8+j];
// B[k=(l>>4)*8+j][n=l&15]; C/D[row=(l>>4)*4+reg][col=l&15].
// Requires M%64==0, N%64==0, K%64==0.
// ---------------------------------------------------------------------------
template<bool A_BF16, bool B_NT, bool C_BF16>
__global__ __launch_bounds__(256) void gemm_mfma(
    const void* __restrict__ Av, const float* __restrict__ B, void* __restrict__ Cv,
    int M, int N, int Kd, int lda, int ldb, int ldc,
    long batchA, long batchB, long batchC)
{
    __shared__ ushort As[64 * 72];
    __shared__ ushort Bs[64 * 72];

    const int tid = threadIdx.x;
    const int w  = tid >> 6;
    const int l  = tid & 63;
    const int lm = l & 15;
    const int kq = l >> 4;
    const int bm = blockIdx.y * 64;
    const int bn = blockIdx.x * 64;
    const int m0 = (w >> 1) * 32;
    const int n0 = (w & 1) * 32;

    const float*  Af = A_BF16 ? nullptr : ((const float*)Av)  + (long)blockIdx.z * batchA;
    const ushort* Ah = A_BF16 ? ((const ushort*)Av) + (long)blockIdx.z * batchA : nullptr;
    B += (long)blockIdx.z * batchB;

    f32x4 acc[2][2];
    #pragma unroll
    for (int i = 0; i < 2; ++i)
        #pragma unroll
        for (int j = 0; j < 2; ++j) acc[i][j] = (f32x4){0.f, 0.f, 0.f, 0.f};

    for (int k0 = 0; k0 < Kd; k0 += 64) {
        __syncthreads();
        // ---- stage A -> As[m][k] bf16 ----
        if constexpr (A_BF16) {
            int m = tid >> 2, ko = (tid & 3) * 16;
            const ushort* src = Ah + (long)(bm + m) * lda + k0 + ko;
            *(uint4*)(As + m * 72 + ko)     = *(const uint4*)(src);
            *(uint4*)(As + m * 72 + ko + 8) = *(const uint4*)(src + 8);
        } else {
            int mr = tid >> 4, kk = (tid & 15) * 4;
            #pragma unroll
            for (int p = 0; p < 4; ++p) {
                int m = mr + p * 16;
                float4 v = *(const float4*)(Af + (long)(bm + m) * lda + k0 + kk);
                ushort4 u;
                u.x = f2bf(v.x); u.y = f2bf(v.y); u.z = f2bf(v.z); u.w = f2bf(v.w);
                *(ushort4*)(As + m * 72 + kk) = u;
            }
        }
        // ---- stage B ----
        if constexpr (B_NT) {
            // rows n-major, contiguous k -> Bs[n][k] pitch 72
            int nr = tid >> 4, kk = (tid & 15) * 4;
            #pragma unroll
            for (int p = 0; p < 4; ++p) {
                int n = nr + p * 16;
                float4 v = *(const float4*)(B + (long)(bn + n) * ldb + k0 + kk);
                ushort4 u;
                u.x = f2bf(v.x); u.y = f2bf(v.y); u.z = f2bf(v.z); u.w = f2bf(v.w);
                *(ushort4*)(Bs + n * 72 + kk) = u;
            }
        } else {
            // row-major [k][n] -> Bs[k][n] pitch 68
            int k = tid >> 2, nq = (tid & 3) * 16;
            #pragma unroll
            for (int p = 0; p < 4; ++p) {
                float4 v = *(const float4*)(B + (long)(k0 + k) * ldb + bn + nq + p * 4);
                ushort4 u;
                u.x = f2bf(v.x); u.y = f2bf(v.y); u.z = f2bf(v.z); u.w = f2bf(v.w);
                *(ushort4*)(Bs + k * 68 + nq + p * 4) = u;
            }
        }
        __syncthreads();
        // ---- compute: 2 k-steps of 32 ----
        #pragma unroll
        for (int ks = 0; ks < 2; ++ks) {
            short8 a[2], b[2];
            #pragma unroll
            for (int mt = 0; mt < 2; ++mt)
                a[mt] = *(const short8*)(As + (m0 + mt * 16 + lm) * 72 + ks * 32 + kq * 8);
            if constexpr (B_NT) {
                #pragma unroll
                for (int nt = 0; nt < 2; ++nt)
                    b[nt] = *(const short8*)(Bs + (n0 + nt * 16 + lm) * 72 + ks * 32 + kq * 8);
            } else {
                #pragma unroll
                for (int nt = 0; nt < 2; ++nt)
                    #pragma unroll
                    for (int j = 0; j < 8; ++j)
                        b[nt][j] = (short)Bs[(ks * 32 + kq * 8 + j) * 68 + n0 + nt * 16 + lm];
            }
            #pragma unroll
            for (int mt = 0; mt < 2; ++mt)
                #pragma unroll
                for (int nt = 0; nt < 2; ++nt)
                    acc[mt][nt] = __builtin_amdgcn_mfma_f32_16x16x32_bf16(
                        a[mt], b[nt], acc[mt][nt], 0, 0, 0);
        }
    }
    // ---- epilogue ----
    #pragma unroll
    for (int mt = 0; mt < 2; ++mt)
        #pragma unroll
        for (int nt = 0; nt < 2; ++nt)
            #pragma unroll
            for (int r = 0; r < 4; ++r) {
                long row = bm + m0 + mt * 16 + kq * 4 + r;
                long col = bn + n0 + nt * 16 + lm;
                if constexpr (C_BF16)
                    ((ushort*)Cv)[(long)blockIdx.z * batchC + row * ldc + col] =
                        f2bf(acc[mt][nt][r]);
                else
                    ((float*)Cv)[(long)blockIdx.z * batchC + row * ldc + col] =
                        acc[mt][nt][r];
            }
}

// ---------------------------------------------------------------------------
// qb[:, :, 512:576] = bf16(rope(q_pe)) from fp32 qfull. fp64 angles.
// ---------------------------------------------------------------------------
__global__ __launch_bounds__(256) void pack_qrope(
    const float* __restrict__ qfull, const int* __restrict__ pos_q,
    ushort* __restrict__ qb)
{
    int id = blockIdx.x * 256 + threadIdx.x;     // T*H*32 = 131072
    int i = id & 31;
    int h = (id >> 5) & 15;
    int t = id >> 9;
    double inv = exp2(-(double)i * 0.41524101186092026);  // 10000^(-i/32)
    double f = (double)pos_q[t] * inv;
    double fr = f - floor(f * 0.15915494309189535) * 6.283185307179586;
    float sf, cf;
    sincosf((float)fr, &sf, &cf);
    float x1 = qfull[t * 3072 + h * 192 + 128 + i];
    float x2 = qfull[t * 3072 + h * 192 + 160 + i];
    ushort* q = qb + (long)(t * 16 + h) * 576;
    q[512 + i] = f2bf(x1 * cf - x2 * sf);
    q[544 + i] = f2bf(x2 * cf + x1 * sf);
}

// ---------------------------------------------------------------------------
// Precompute kvb[s][0:512]=bf16(kv_c[s]), kvb[s][512:576]=bf16(rope(k_pe[s],s)).
// (round-0 HW-verified form; 72 lanes/row)
// ---------------------------------------------------------------------------
__global__ __launch_bounds__(256) void prep_kvb(
    const float* __restrict__ kvc, const float* __restrict__ kpe,
    ushort* __restrict__ kvb)
{
    int id = blockIdx.x * 256 + threadIdx.x;   // 32768*72 = 2,359,296
    int s = id / 72;
    int c = id - s * 72;
    if (c < 64) {
        const float* src = kvc + (long)s * 512 + c * 8;
        float4 v0 = *(const float4*)src;
        float4 v1 = *(const float4*)(src + 4);
        ushort4 a, b;
        a.x = f2bf(v0.x); a.y = f2bf(v0.y); a.z = f2bf(v0.z); a.w = f2bf(v0.w);
        b.x = f2bf(v1.x); b.y = f2bf(v1.y); b.z = f2bf(v1.z); b.w = f2bf(v1.w);
        ushort* dst = kvb + (long)s * 576 + c * 8;
        *(ushort4*)dst = a;
        *(ushort4*)(dst + 4) = b;
    } else {
        int q = c - 64;                       // 0..7 -> rope dims q*8..q*8+7
        const float* kp = kpe + (long)s * 64;
        ushort* dst = kvb + (long)s * 576 + 512 + q * 8;
        #pragma unroll
        for (int e = 0; e < 8; ++e) {
            int d = q * 8 + e;
            int i = d & 31;
            double inv = exp2(-(double)i * 0.41524101186092026);
            double f = (double)s * inv;
            double fr = f - floor(f * 0.15915494309189535) * 6.283185307179586;
            float sf, cf;
            sincosf((float)fr, &sf, &cf);
            float x1 = kp[i], x2 = kp[32 + i];
            dst[e] = (d < 32) ? f2bf(x1 * cf - x2 * sf) : f2bf(x2 * cf + x1 * sf);
        }
    }
}

// ---------------------------------------------------------------------------
// Fused flash-MLA attention, split-K=2 (512 blocks, 2/CU). Gathers pre-packed
// bf16 kvb rows. Emits unnormalized partial O (bf16) + (m,l) fp32.
//
// LDS key-tile layout, subtiled (bijective):
//   off(s,d) = (d>>4)*2048 + (s>>2)*128 + (s&3)*32 + (d&15)*2
// Each 128B subtile is a 4x16 row-major [key][dim] bf16 tile.
//
// ds_read_b64_tr_b16 TRUE SEMANTICS (round-3 fix; unique model fitting
// m156 + m162): each lane does a plain 64-bit read AT ITS OWN ADDRESS
// (m162: uniform addr -> same value, no internal lane offset); the HW then
// cross-lane-exchanges within each 16-lane group: with the group's reads
// concatenated lane-major into a 64-elem block, lane l elem j receives
// block elem (l&15)+16*j (m156's canonical formula). Therefore the correct
// addressing is lane (l&15) -> tile_base + (l&15)*8 (each lane owns one
// 8-byte chunk of the 4x16 tile), and the delivered fragment is
// elem j = tile[key j][dim l&15]. Rounds 1-3 passed tile_base + (l&15)*2
// (column address, assuming a per-lane stride-32 gather) -> the exchange
// scrambled head/v with key on BOTH P and V operands; identical scrambling
// does NOT cancel through MFMA (A indexed by m, B by n) -> the layout-
// independent ~5.4e-2 absmax seen in all three rounds.
//
// P is stored key-subtiled the same way: off_P(k,h)=(k>>2)*128+(k&3)*32+h*2
// so the A-operand (P[h=lm][key kq*8+j]) comes from the same tr-read pattern.
// ---------------------------------------------------------------------------
#define KBD 2048    // d-block pitch in bytes (16 subtiles * 128B, dense)

__global__ __launch_bounds__(256, 1) void mla_fused_split(
    const ushort* __restrict__ qb, const ushort* __restrict__ kvb,
    const int* __restrict__ topk,
    ushort* __restrict__ Opart, float* __restrict__ ml)
{
    __shared__ __align__(16) char kb[36 * KBD];   // 73,728 B
    __shared__ __align__(16) ushort P2[1024];     // P, key-subtiled (2 KiB)
    __shared__ float wred[2][4][16];              // [max|sum][wave][row]

    const int t = blockIdx.x;
    const int sp = blockIdx.y;          // split 0/1
    const int tid = threadIdx.x;
    const int w = tid >> 6;
    const int l = tid & 63;
    const int lm = l & 15;
    const int kq = l >> 4;

    // ---- preload Q A-fragments (18 k-steps of 32) ----
    short8 qa[18];
    {
        const ushort* qrow = qb + (long)(t * 16 + lm) * 576 + kq * 8;
        #pragma unroll
        for (int ks = 0; ks < 18; ++ks)
            qa[ks] = *(const short8*)(qrow + ks * 32);
    }

    const int skk = tid >> 2;        // staging: key row 0..63
    const int sq = tid & 3;          // quarter (16B chunk of 64B span)
    const int* tkp = topk + (long)t * 2048 + sp * 1024;

    // staging dst base: key skk, dim chunk d = sq*8 (+32 per i -> +2 d-blocks)
    char* sdst = kb + (sq >> 1) * KBD + (skk >> 2) * 128
               + (skk & 3) * 32 + (sq & 1) * 16;

    // QK B-fragment base: key = w*16+lm (subtile w*4+(lm>>2), slot lm&3),
    // dim = ks*32 + kq*8 (d-block 2ks+(kq>>1), halfword (kq&1)*16B)
    const char* krow = kb + (kq >> 1) * KBD + w * 512 + (lm >> 2) * 128
                     + (lm & 3) * 32 + (kq & 1) * 16;

    // PV tr-read bases: group kq reads key-quads 2kq/2kq+1 (+8 per ks);
    // lane lm owns the lm-th 8-byte chunk of the 4x16 tile (lm*8 — the fix).
    const unsigned trbase = (unsigned)(unsigned long long)(const void*)kb
                          + (unsigned)(w * 8 * KBD + kq * 256 + lm * 8);
    const unsigned ptrb = (unsigned)(unsigned long long)(const void*)P2
                        + (unsigned)(kq * 256 + lm * 8);

    f32x4 O[8];
    #pragma unroll
    for (int vt = 0; vt < 8; ++vt) O[vt] = (f32x4){0.f, 0.f, 0.f, 0.f};
    float m_r[4] = {-1e30f, -1e30f, -1e30f, -1e30f};
    float l_r[4] = {0.f, 0.f, 0.f, 0.f};

    for (int kt = 0; kt < 1024; kt += 64) {
        __syncthreads();
        {   // gather pre-packed bf16 row into subtiled layout
            int idx = tkp[kt + skk];
            const ushort* src = kvb + (long)idx * 576 + sq * 8;
            #pragma unroll
            for (int i = 0; i < 18; ++i)
                *(uint4*)(sdst + i * (2 * KBD)) = *(const uint4*)(src + i * 32);
        }
        __syncthreads();

        // ---- S = Q . K^T for this wave's 16 keys ----
        f32x4 S = (f32x4){0.f, 0.f, 0.f, 0.f};
        {
            #pragma unroll
            for (int ks = 0; ks < 18; ++ks) {
                short8 bf = *(const short8*)(krow + ks * (2 * KBD));
                S = __builtin_amdgcn_mfma_f32_16x16x32_bf16(qa[ks], bf, S, 0, 0, 0);
            }
        }
        float s4[4], mx[4], p[4];
        #pragma unroll
        for (int r = 0; r < 4; ++r) { s4[r] = S[r] * SCALE_; mx[r] = s4[r]; }
        #pragma unroll
        for (int off = 1; off < 16; off <<= 1)
            #pragma unroll
            for (int r = 0; r < 4; ++r)
                mx[r] = fmaxf(mx[r], __shfl_xor(mx[r], off, 64));
        if (lm == 0)
            #pragma unroll
            for (int r = 0; r < 4; ++r) wred[0][w][4 * kq + r] = mx[r];
        __syncthreads();

        float al[4], rs[4];
        #pragma unroll
        for (int r = 0; r < 4; ++r) {
            float tm = fmaxf(fmaxf(wred[0][0][4 * kq + r], wred[0][1][4 * kq + r]),
                             fmaxf(wred[0][2][4 * kq + r], wred[0][3][4 * kq + r]));
            float mn = fmaxf(m_r[r], tm);
            al[r] = exp2f((m_r[r] - mn) * LOG2E_);
            p[r] = exp2f((s4[r] - mn) * LOG2E_);
            m_r[r] = mn;
            rs[r] = p[r];
        }
        #pragma unroll
        for (int off = 1; off < 16; off <<= 1)
            #pragma unroll
            for (int r = 0; r < 4; ++r)
                rs[r] += __shfl_xor(rs[r], off, 64);
        if (lm == 0)
            #pragma unroll
            for (int r = 0; r < 4; ++r) wred[1][w][4 * kq + r] = rs[r];
        // P write: key = w*16+lm, heads 4kq..4kq+3 consecutive -> one b64 store
        {
            ushort4 pu;
            pu.x = f2bf(p[0]); pu.y = f2bf(p[1]);
            pu.z = f2bf(p[2]); pu.w = f2bf(p[3]);
            *(ushort4*)(P2 + (w * 4 + (lm >> 2)) * 64 + (lm & 3) * 16 + 4 * kq) = pu;
        }
        #pragma unroll
        for (int vt = 0; vt < 8; ++vt)
            #pragma unroll
            for (int r = 0; r < 4; ++r)
                O[vt][r] *= al[r];
        __syncthreads();   // P2 + wred[1] visible

        #pragma unroll
        for (int r = 0; r < 4; ++r) {
            float ts = wred[1][0][4 * kq + r] + wred[1][1][4 * kq + r] +
                       wred[1][2][4 * kq + r] + wred[1][3][4 * kq + r];
            l_r[r] = l_r[r] * al[r] + ts;
        }

        // ---- O += P . V (wave's 128-wide v range) ----
        // P via tr reads with the SAME relative pattern as V (see header note)
        short4v pr[4];
        asm volatile("ds_read_b64_tr_b16 %0, %1 offset:0"    : "=v"(pr[0]) : "v"(ptrb));
        asm volatile("ds_read_b64_tr_b16 %0, %1 offset:128"  : "=v"(pr[1]) : "v"(ptrb));
        asm volatile("ds_read_b64_tr_b16 %0, %1 offset:1024" : "=v"(pr[2]) : "v"(ptrb));
        asm volatile("ds_read_b64_tr_b16 %0, %1 offset:1152" : "=v"(pr[3]) : "v"(ptrb));

        short4v r[32];
        #pragma unroll
        for (int ks = 0; ks < 2; ++ks)
            #pragma unroll
            for (int vt = 0; vt < 8; ++vt) {
                asm volatile("ds_read_b64_tr_b16 %0, %1 offset:%2"
                    : "=v"(r[ks * 16 + 2 * vt])
                    : "v"(trbase), "i"(vt * KBD + ks * 1024));
                asm volatile("ds_read_b64_tr_b16 %0, %1 offset:%2"
                    : "=v"(r[ks * 16 + 2 * vt + 1])
                    : "v"(trbase), "i"(vt * KBD + ks * 1024 + 128));
            }
        asm volatile("s_waitcnt lgkmcnt(0)" ::: "memory");
        __builtin_amdgcn_sched_barrier(0);

        short8 pa[2];
        pa[0] = __builtin_shufflevector(pr[0], pr[1], 0, 1, 2, 3, 4, 5, 6, 7);
        pa[1] = __builtin_shufflevector(pr[2], pr[3], 0, 1, 2, 3, 4, 5, 6, 7);
        #pragma unroll
        for (int ks = 0; ks < 2; ++ks)
            #pragma unroll
            for (int vt = 0; vt < 8; ++vt) {
                short8 bv = __builtin_shufflevector(
                    r[ks * 16 + 2 * vt], r[ks * 16 + 2 * vt + 1],
                    0, 1, 2, 3, 4, 5, 6, 7);
                O[vt] = __builtin_amdgcn_mfma_f32_16x16x32_bf16(pa[ks], bv, O[vt], 0, 0, 0);
            }
    }

    // ---- epilogue: store unnormalized partial O (bf16) + (m,l) ----
    const long rbase = ((long)sp * 256 + t) * 16;
    #pragma unroll
    for (int vt = 0; vt < 8; ++vt)
        #pragma unroll
        for (int r = 0; r < 4; ++r)
            Opart[(rbase + 4 * kq + r) * 512 + w * 128 + vt * 16 + lm] = f2bf(O[vt][r]);
    if (w == 0 && lm == 0) {
        #pragma unroll
        for (int r = 0; r < 4; ++r) {
            ml[(rbase + 4 * kq + r) * 2 + 0] = m_r[r];
            ml[(rbase + 4 * kq + r) * 2 + 1] = l_r[r];
        }
    }
}

// ---------------------------------------------------------------------------
// Merge the 2 split-K partials -> olat bf16.
// ---------------------------------------------------------------------------
__global__ __launch_bounds__(256) void combine_kernel(
    const ushort* __restrict__ Opart, const float* __restrict__ ml,
    ushort* __restrict__ olat)
{
    const int t = blockIdx.x;
    const int h = threadIdx.x >> 4;
    const int v0 = (threadIdx.x & 15) * 32;
    const long r0 = (long)t * 16 + h;
    const long r1 = (long)(256 + t) * 16 + h;
    float m0 = ml[r0 * 2], l0 = ml[r0 * 2 + 1];
    float m1 = ml[r1 * 2], l1 = ml[r1 * 2 + 1];
    float M = fmaxf(m0, m1);
    float w0 = exp2f((m0 - M) * LOG2E_);
    float w1 = exp2f((m1 - M) * LOG2E_);
    float inv = 1.0f / (w0 * l0 + w1 * l1);
    const ushort* p0 = Opart + r0 * 512 + v0;
    const ushort* p1 = Opart + r1 * 512 + v0;
    ushort* po = olat + r0 * 512 + v0;
    #pragma unroll
    for (int i = 0; i < 32; i += 4) {
        ushort4 a = *(const ushort4*)(p0 + i);
        ushort4 b = *(const ushort4*)(p1 + i);
        ushort4 o;
        o.x = f2bf((w0 * bf2f(a.x) + w1 * bf2f(b.x)) * inv);
        o.y = f2bf((w0 * bf2f(a.y) + w1 * bf2f(b.y)) * inv);
        o.z = f2bf((w0 * bf2f(a.z) + w1 * bf2f(b.z)) * inv);
        o.w = f2bf((w0 * bf2f(a.w) + w1 * bf2f(b.w)) * inv);
        *(ushort4*)(po + i) = o;
    }
}

// ---------------------------------------------------------------------------
// Launch. ws footprint exactly 54,001,664 B (proven safe in R5).
// Layout (bytes):
//   qb    [0,          4,718,592)   bf16 q per head, 576/row
//   qfull [4,718,592,  7,864,320)   fp32 (dead after GEMM2+pack_qrope)
//   Opart [4,718,592, 13,107,200)   overlay (written in attention)
//   ov_b  [13,107,200, 14,155,776)  bf16
//   ml    [14,155,776, 14,221,312)
//   kvb   [16,252,928, 54,001,664)  bf16 kv table (unchanged address)
//   olat = overlay of qb [0, 4,194,304) (qb dead after attention)
// ---------------------------------------------------------------------------
extern "C" void kernel_launch(void* const* d_in, const int* in_sizes, int n_in,
                              void* d_out, int out_size, void* d_ws, size_t ws_size,
                              hipStream_t stream)
{
    const float* x    = (const float*)d_in[0];
    const float* Wq   = (const float*)d_in[1];
    const float* W_UK = (const float*)d_in[2];
    const float* W_UV = (const float*)d_in[3];
    const float* Wo   = (const float*)d_in[4];
    const float* kv_c = (const float*)d_in[5];
    const float* k_pe = (const float*)d_in[6];
    const int* topk   = (const int*)d_in[7];
    const int* pos_q  = (const int*)d_in[8];
    float* out        = (float*)d_out;

    char* wsb = (char*)d_ws;
    ushort* qb    = (ushort*)wsb;
    float*  qfull = (float*)(wsb + 4718592);
    ushort* Opart = (ushort*)(wsb + 4718592);          // overlay of qfull
    ushort* ov_b  = (ushort*)(wsb + 13107200);
    float*  ml    = (float*)(wsb + 14155776);
    ushort* olat  = qb;                                // overlay (qb dead)
    ushort* kvb   = (ushort*)(wsb + 16252928);
    if (ws_size < (size_t)54001664) return;            // fail loud, don't fault

    // 0) prep bf16 kv table
    prep_kvb<<<9216, 256, 0, stream>>>(kv_c, k_pe, kvb);

    // 1) qfull = x @ Wq   (256 x 3072 x 2048), fp32 out
    gemm_mfma<false, false, false><<<dim3(48, 4), 256, 0, stream>>>(
        x, Wq, qfull, 256, 3072, 2048, 2048, 3072, 3072, 0, 0, 0);

    // 2) qb[:, :, 0:512] = qnope @ W_UK[h]  (256 x 512 x 128, batched over h)
    //    C row m=t -> qb[(t*16+h)*576 + n]: ldc = 16*576, base offset h*576
    gemm_mfma<false, false, true><<<dim3(8, 4, 16), 256, 0, stream>>>(
        qfull, W_UK, qb, 256, 512, 128, 3072, 512, 9216, 192, 65536, 576);

    // 3) qb[:, :, 512:576] = bf16(rope(q_pe))
    pack_qrope<<<512, 256, 0, stream>>>(qfull, pos_q, qb);

    // 4) fused attention, split-K=2 -> partials
    mla_fused_split<<<dim3(256, 2), 256, 0, stream>>>(qb, kvb, topk, Opart, ml);

    // 5) combine partials -> olat (bf16, overlays qb)
    combine_kernel<<<256, 256, 0, stream>>>(Opart, ml, olat);

    // 6) ov_b[t, h*128+v] = olat[t,h,:] . W_UV[h,v,:]  (NT, A bf16, C bf16)
    gemm_mfma<true, true, true><<<dim3(2, 4, 16), 256, 0, stream>>>(
        olat, W_UV, ov_b, 256, 128, 512, 8192, 512, 2048, 512, 65536, 128);

    // 7) out = ov_b @ Wo   (256 x 2048 x 2048), fp32 out
    gemm_mfma<true, false, false><<<dim3(32, 4), 256, 0, stream>>>(
        ov_b, Wo, out, 256, 2048, 2048, 2048, 2048, 2048, 0, 0, 0);
}